// Round 1
// baseline (15330.827 us; speedup 1.0000x reference)
//
#include <hip/hip_runtime.h>
#include <math.h>

// FCLTCQNetwork: liquid-time-constant cell scan + MLP head.
// B=4096 T=128 D=64 U=64 A=8 QH=64 UNFOLDS=6.
// One wave per batch element; lane = target neuron index i.
// Params pre-transformed into LDS once per block:
//   sigmoid(sigma*(x-mu)) = rcp(1 + exp2(k*x + c)), k=-log2e*sigma, c=log2e*sigma*mu
//   ws = softplus(w)*erev  (signed; |ws| = softplus(w) since erev=+-1)

namespace {

constexpr int kB = 4096, kT = 128, kD = 64, kU = 64, kA = 8, kQH = 64, kUnf = 6;
constexpr float kEps = 1e-8f;
constexpr float kLog2e = 1.4426950408889634f;
constexpr int kWaves = 16;            // waves (batch elements) per block
constexpr int kBlock = kWaves * 64;   // 1024 threads

#if __has_builtin(__builtin_amdgcn_exp2f)
#define EXP2F(x) __builtin_amdgcn_exp2f(x)
#else
#define EXP2F(x) exp2f(x)
#endif

__device__ __forceinline__ float rcp_fast(float x) {
  return __builtin_amdgcn_rcpf(x);
}

__device__ __forceinline__ float bcast(float x, int l) {
  return __int_as_float(__builtin_amdgcn_readlane(__float_as_int(x), l));
}

__device__ __forceinline__ float softplus(float x) { return log1pf(expf(x)); }

__global__ __launch_bounds__(kBlock, 1)
void ltc_fused(const float* __restrict__ obs, const float* __restrict__ input_w,
               const float* __restrict__ input_b, const float* __restrict__ s_mu,
               const float* __restrict__ s_sigma, const float* __restrict__ s_w,
               const float* __restrict__ s_erev, const float* __restrict__ r_mu,
               const float* __restrict__ r_sigma, const float* __restrict__ r_w,
               const float* __restrict__ r_erev, const float* __restrict__ gleak,
               const float* __restrict__ vleak, const float* __restrict__ cm,
               const float* __restrict__ W1, const float* __restrict__ b1,
               const float* __restrict__ W2, const float* __restrict__ b2,
               float* __restrict__ q_out, float* __restrict__ h_out) {
  // LDS-packed transformed params: 32KB + 16KB + 32KB + 16KB = 96KB
  __shared__ float2 skc[kD * kU];  // sensory (k, c), layout [d][i]
  __shared__ float  sws[kD * kU];  // sensory signed weight
  __shared__ float2 rkc[kU * kU];  // recurrent (k, c), layout [j][i]
  __shared__ float  rws[kU * kU];  // recurrent signed weight

  const int tid = threadIdx.x;
  for (int idx = tid; idx < kD * kU; idx += kBlock) {
    const float sg = s_sigma[idx];
    skc[idx] = make_float2(-kLog2e * sg, kLog2e * sg * s_mu[idx]);
    sws[idx] = softplus(s_w[idx]) * s_erev[idx];
    const float rg = r_sigma[idx];
    rkc[idx] = make_float2(-kLog2e * rg, kLog2e * rg * r_mu[idx]);
    rws[idx] = softplus(r_w[idx]) * r_erev[idx];
  }
  __syncthreads();

  const int lane = tid & 63;
  const int b = blockIdx.x * kWaves + (tid >> 6);

  // Per-neuron (lane = i) scalars.
  const float gl   = softplus(gleak[lane]);
  const float glvl = gl * vleak[lane];
  const float cmt  = softplus(cm[lane]) * (float)kUnf;
  const float iw   = input_w[lane];
  const float ib   = input_b[lane];

  const float* obs_b = obs + (size_t)b * kT * kD;
  float v = 0.0f;

#pragma unroll 1
  for (int t = 0; t < kT; ++t) {
    const float xi = fmaf(obs_b[t * kD + lane], iw, ib);

    // Sensory synapse sums (depend only on x; once per timestep).
    float ns = 0.0f, dss = 0.0f;
#pragma unroll
    for (int d = 0; d < kD; ++d) {
      const float xd = bcast(xi, d);
      const float2 kc = skc[d * kU + lane];
      const float e = EXP2F(fmaf(kc.x, xd, kc.y));
      const float sig = rcp_fast(1.0f + e);
      const float w = sws[d * kU + lane];
      ns  = fmaf(sig, w, ns);
      dss = fmaf(sig, fabsf(w), dss);
    }

    // ODE unfolds.
#pragma unroll 1
    for (int u = 0; u < kUnf; ++u) {
      float num = 0.0f, den = 0.0f;
#pragma unroll
      for (int j = 0; j < kU; ++j) {
        const float vj = bcast(v, j);
        const float2 kc = rkc[j * kU + lane];
        const float e = EXP2F(fmaf(kc.x, vj, kc.y));
        const float sig = rcp_fast(1.0f + e);
        const float w = rws[j * kU + lane];
        num = fmaf(sig, w, num);
        den = fmaf(sig, fabsf(w), den);
      }
      const float ntot = fmaf(cmt, v, glvl) + num + ns;
      const float dtot = cmt + gl + den + dss + kEps;
      v = ntot * rcp_fast(dtot);
    }
  }

  // hidden output
  h_out[(size_t)b * kU + lane] = v;

  // Head: h1 = relu(v @ W1 + b1); q = h1 @ W2 + b2. Once per batch, cheap.
  float h1 = b1[lane];
#pragma unroll
  for (int j = 0; j < kU; ++j) {
    h1 = fmaf(bcast(v, j), W1[j * kQH + lane], h1);
  }
  h1 = fmaxf(h1, 0.0f);

  float qa[kA];
#pragma unroll
  for (int a = 0; a < kA; ++a) qa[a] = h1 * W2[lane * kA + a];
#pragma unroll
  for (int s = 32; s > 0; s >>= 1) {
#pragma unroll
    for (int a = 0; a < kA; ++a) qa[a] += __shfl_xor(qa[a], s, 64);
  }
  if (lane == 0) {
#pragma unroll
    for (int a = 0; a < kA; ++a) q_out[(size_t)b * kA + a] = qa[a] + b2[a];
  }
}

}  // namespace

extern "C" void kernel_launch(void* const* d_in, const int* in_sizes, int n_in,
                              void* d_out, int out_size, void* d_ws, size_t ws_size,
                              hipStream_t stream) {
  const float* obs     = (const float*)d_in[0];
  const float* input_w = (const float*)d_in[1];
  const float* input_b = (const float*)d_in[2];
  const float* s_mu    = (const float*)d_in[3];
  const float* s_sigma = (const float*)d_in[4];
  const float* s_w     = (const float*)d_in[5];
  const float* s_erev  = (const float*)d_in[6];
  const float* r_mu    = (const float*)d_in[7];
  const float* r_sigma = (const float*)d_in[8];
  const float* r_w     = (const float*)d_in[9];
  const float* r_erev  = (const float*)d_in[10];
  const float* gleak   = (const float*)d_in[11];
  const float* vleak   = (const float*)d_in[12];
  const float* cm      = (const float*)d_in[13];
  const float* W1      = (const float*)d_in[14];
  const float* b1      = (const float*)d_in[15];
  const float* W2      = (const float*)d_in[16];
  const float* b2      = (const float*)d_in[17];

  float* q_out = (float*)d_out;
  float* h_out = q_out + (size_t)kB * kA;

  hipLaunchKernelGGL(ltc_fused, dim3(kB / kWaves), dim3(kBlock), 0, stream,
                     obs, input_w, input_b, s_mu, s_sigma, s_w, s_erev,
                     r_mu, r_sigma, r_w, r_erev, gleak, vleak, cm,
                     W1, b1, W2, b2, q_out, h_out);
}

// Round 2
// 7697.124 us; speedup vs baseline: 1.9918x; 1.9918x over previous
//
#include <hip/hip_runtime.h>
#include <math.h>

// FCLTCQNetwork: liquid-time-constant cell scan + MLP head.
// B=4096 T=128 D=64 U=64 A=8 QH=64 UNFOLDS=6.
// Round 1: 8 waves/block, TWO batch elements per wave sharing each LDS param
// read (halves LDS pipe cycles per element, doubles ILP), obs prefetch.
// lane = target neuron index i.
// Params pre-transformed into LDS once per block:
//   sigmoid(sigma*(x-mu)) = rcp(1 + exp2(k*x + c)), k=-log2e*sigma, c=log2e*sigma*mu
//   ws = softplus(w)*erev  (signed; |ws| = softplus(w) since erev=+-1)

namespace {

constexpr int kB = 4096, kT = 128, kD = 64, kU = 64, kA = 8, kQH = 64, kUnf = 6;
constexpr float kEps = 1e-8f;
constexpr float kLog2e = 1.4426950408889634f;
constexpr int kWaves = 8;             // waves per block
constexpr int kEPW = 2;               // batch elements per wave
constexpr int kBlock = kWaves * 64;   // 512 threads
constexpr int kBPB = kWaves * kEPW;   // 16 batch elements per block

#if __has_builtin(__builtin_amdgcn_exp2f)
#define EXP2F(x) __builtin_amdgcn_exp2f(x)
#else
#define EXP2F(x) exp2f(x)
#endif

__device__ __forceinline__ float rcp_fast(float x) {
  return __builtin_amdgcn_rcpf(x);
}

__device__ __forceinline__ float bcast(float x, int l) {
  return __int_as_float(__builtin_amdgcn_readlane(__float_as_int(x), l));
}

__device__ __forceinline__ float softplus(float x) { return log1pf(expf(x)); }

__global__ __launch_bounds__(kBlock, 2)
void ltc_fused(const float* __restrict__ obs, const float* __restrict__ input_w,
               const float* __restrict__ input_b, const float* __restrict__ s_mu,
               const float* __restrict__ s_sigma, const float* __restrict__ s_w,
               const float* __restrict__ s_erev, const float* __restrict__ r_mu,
               const float* __restrict__ r_sigma, const float* __restrict__ r_w,
               const float* __restrict__ r_erev, const float* __restrict__ gleak,
               const float* __restrict__ vleak, const float* __restrict__ cm,
               const float* __restrict__ W1, const float* __restrict__ b1,
               const float* __restrict__ W2, const float* __restrict__ b2,
               float* __restrict__ q_out, float* __restrict__ h_out) {
  // LDS-packed transformed params: 32KB + 16KB + 32KB + 16KB = 96KB
  __shared__ float2 skc[kD * kU];  // sensory (k, c), layout [d][i]
  __shared__ float  sws[kD * kU];  // sensory signed weight
  __shared__ float2 rkc[kU * kU];  // recurrent (k, c), layout [j][i]
  __shared__ float  rws[kU * kU];  // recurrent signed weight

  const int tid = threadIdx.x;
  for (int idx = tid; idx < kD * kU; idx += kBlock) {
    const float sg = s_sigma[idx];
    skc[idx] = make_float2(-kLog2e * sg, kLog2e * sg * s_mu[idx]);
    sws[idx] = softplus(s_w[idx]) * s_erev[idx];
    const float rg = r_sigma[idx];
    rkc[idx] = make_float2(-kLog2e * rg, kLog2e * rg * r_mu[idx]);
    rws[idx] = softplus(r_w[idx]) * r_erev[idx];
  }
  __syncthreads();

  const int lane = tid & 63;
  const int wid = tid >> 6;
  const int b0 = (blockIdx.x * kWaves + wid) * kEPW;  // this wave's 2 elements

  // Per-neuron (lane = i) scalars.
  const float gl   = softplus(gleak[lane]);
  const float glvl = gl * vleak[lane];
  const float cmt  = softplus(cm[lane]) * (float)kUnf;
  const float iw   = input_w[lane];
  const float ib   = input_b[lane];

  const float* obs0 = obs + (size_t)b0 * kT * kD;
  const float* obs1 = obs0 + (size_t)kT * kD;
  float v0 = 0.0f, v1 = 0.0f;

  // prefetched observations for the current timestep
  float o0 = obs0[lane];
  float o1 = obs1[lane];

#pragma unroll 1
  for (int t = 0; t < kT; ++t) {
    // prefetch next timestep's obs; latency hides behind this iteration's body
    const int tn = (t + 1 < kT) ? (t + 1) : t;
    const float n0 = obs0[tn * kD + lane];
    const float n1 = obs1[tn * kD + lane];

    const float xi0 = fmaf(o0, iw, ib);
    const float xi1 = fmaf(o1, iw, ib);

    // Sensory synapse sums (depend only on x; once per timestep).
    float ns0 = 0.0f, ds0 = 0.0f, ns1 = 0.0f, ds1 = 0.0f;
#pragma unroll
    for (int d = 0; d < kD; ++d) {
      const float2 kc = skc[d * kU + lane];
      const float w = sws[d * kU + lane];
      const float xd0 = bcast(xi0, d);
      const float xd1 = bcast(xi1, d);
      const float e0 = EXP2F(fmaf(kc.x, xd0, kc.y));
      const float e1 = EXP2F(fmaf(kc.x, xd1, kc.y));
      const float g0 = rcp_fast(1.0f + e0);
      const float g1 = rcp_fast(1.0f + e1);
      ns0 = fmaf(g0, w, ns0);
      ds0 = fmaf(g0, fabsf(w), ds0);
      ns1 = fmaf(g1, w, ns1);
      ds1 = fmaf(g1, fabsf(w), ds1);
    }

    // ODE unfolds.
#pragma unroll 1
    for (int u = 0; u < kUnf; ++u) {
      float num0 = 0.0f, den0 = 0.0f, num1 = 0.0f, den1 = 0.0f;
#pragma unroll
      for (int j = 0; j < kU; ++j) {
        const float2 kc = rkc[j * kU + lane];
        const float w = rws[j * kU + lane];
        const float vj0 = bcast(v0, j);
        const float vj1 = bcast(v1, j);
        const float e0 = EXP2F(fmaf(kc.x, vj0, kc.y));
        const float e1 = EXP2F(fmaf(kc.x, vj1, kc.y));
        const float g0 = rcp_fast(1.0f + e0);
        const float g1 = rcp_fast(1.0f + e1);
        num0 = fmaf(g0, w, num0);
        den0 = fmaf(g0, fabsf(w), den0);
        num1 = fmaf(g1, w, num1);
        den1 = fmaf(g1, fabsf(w), den1);
      }
      const float nt0 = fmaf(cmt, v0, glvl) + num0 + ns0;
      const float dt0 = cmt + gl + den0 + ds0 + kEps;
      v0 = nt0 * rcp_fast(dt0);
      const float nt1 = fmaf(cmt, v1, glvl) + num1 + ns1;
      const float dt1 = cmt + gl + den1 + ds1 + kEps;
      v1 = nt1 * rcp_fast(dt1);
    }

    o0 = n0;
    o1 = n1;
  }

  // hidden output
  h_out[(size_t)b0 * kU + lane] = v0;
  h_out[(size_t)(b0 + 1) * kU + lane] = v1;

  // Head: h1 = relu(v @ W1 + b1); q = h1 @ W2 + b2. Once per batch, cheap.
  float h10 = b1[lane], h11 = b1[lane];
#pragma unroll
  for (int j = 0; j < kU; ++j) {
    const float w1 = W1[j * kQH + lane];
    h10 = fmaf(bcast(v0, j), w1, h10);
    h11 = fmaf(bcast(v1, j), w1, h11);
  }
  h10 = fmaxf(h10, 0.0f);
  h11 = fmaxf(h11, 0.0f);

  float qa0[kA], qa1[kA];
#pragma unroll
  for (int a = 0; a < kA; ++a) {
    const float w2 = W2[lane * kA + a];
    qa0[a] = h10 * w2;
    qa1[a] = h11 * w2;
  }
#pragma unroll
  for (int s = 32; s > 0; s >>= 1) {
#pragma unroll
    for (int a = 0; a < kA; ++a) {
      qa0[a] += __shfl_xor(qa0[a], s, 64);
      qa1[a] += __shfl_xor(qa1[a], s, 64);
    }
  }
  if (lane == 0) {
#pragma unroll
    for (int a = 0; a < kA; ++a) {
      q_out[(size_t)b0 * kA + a] = qa0[a] + b2[a];
      q_out[(size_t)(b0 + 1) * kA + a] = qa1[a] + b2[a];
    }
  }
}

}  // namespace

extern "C" void kernel_launch(void* const* d_in, const int* in_sizes, int n_in,
                              void* d_out, int out_size, void* d_ws, size_t ws_size,
                              hipStream_t stream) {
  const float* obs     = (const float*)d_in[0];
  const float* input_w = (const float*)d_in[1];
  const float* input_b = (const float*)d_in[2];
  const float* s_mu    = (const float*)d_in[3];
  const float* s_sigma = (const float*)d_in[4];
  const float* s_w     = (const float*)d_in[5];
  const float* s_erev  = (const float*)d_in[6];
  const float* r_mu    = (const float*)d_in[7];
  const float* r_sigma = (const float*)d_in[8];
  const float* r_w     = (const float*)d_in[9];
  const float* r_erev  = (const float*)d_in[10];
  const float* gleak   = (const float*)d_in[11];
  const float* vleak   = (const float*)d_in[12];
  const float* cm      = (const float*)d_in[13];
  const float* W1      = (const float*)d_in[14];
  const float* b1      = (const float*)d_in[15];
  const float* W2      = (const float*)d_in[16];
  const float* b2      = (const float*)d_in[17];

  float* q_out = (float*)d_out;
  float* h_out = q_out + (size_t)kB * kA;

  hipLaunchKernelGGL(ltc_fused, dim3(kB / kBPB), dim3(kBlock), 0, stream,
                     obs, input_w, input_b, s_mu, s_sigma, s_w, s_erev,
                     r_mu, r_sigma, r_w, r_erev, gleak, vleak, cm,
                     W1, b1, W2, b2, q_out, h_out);
}

// Round 3
// 3975.881 us; speedup vs baseline: 3.8560x; 1.9360x over previous
//
#include <hip/hip_runtime.h>
#include <math.h>

// FCLTCQNetwork: liquid-time-constant cell scan + MLP head.
// B=4096 T=128 D=64 U=64 A=8 QH=64 UNFOLDS=6.
// Round 2: 4 waves/block, FOUR batch elements per wave (1 wave/SIMD, 256
// blocks = 1 block/CU). Params packed as float4 (k, c, w_signed, |w|) so the
// inner term does ONE ds_read_b128 + per-element {readlane, fma, exp2, add,
// rcp, fma, fma}.
//   sigmoid(sigma*(x-mu)) = rcp(1 + exp2(k*x + c)), k=-log2e*sigma, c=log2e*sigma*mu

namespace {

constexpr int kB = 4096, kT = 128, kD = 64, kU = 64, kA = 8, kQH = 64, kUnf = 6;
constexpr float kEps = 1e-8f;
constexpr float kLog2e = 1.4426950408889634f;
constexpr int kWaves = 4;             // waves per block
constexpr int kEPW = 4;               // batch elements per wave
constexpr int kBlock = kWaves * 64;   // 256 threads
constexpr int kBPB = kWaves * kEPW;   // 16 batch elements per block

#if __has_builtin(__builtin_amdgcn_exp2f)
#define EXP2F(x) __builtin_amdgcn_exp2f(x)
#else
#define EXP2F(x) exp2f(x)
#endif

__device__ __forceinline__ float rcp_fast(float x) {
  return __builtin_amdgcn_rcpf(x);
}

__device__ __forceinline__ float bcast(float x, int l) {
  return __int_as_float(__builtin_amdgcn_readlane(__float_as_int(x), l));
}

__device__ __forceinline__ float softplus(float x) { return log1pf(expf(x)); }

__global__ __launch_bounds__(kBlock, 1)
void ltc_fused(const float* __restrict__ obs, const float* __restrict__ input_w,
               const float* __restrict__ input_b, const float* __restrict__ s_mu,
               const float* __restrict__ s_sigma, const float* __restrict__ s_w,
               const float* __restrict__ s_erev, const float* __restrict__ r_mu,
               const float* __restrict__ r_sigma, const float* __restrict__ r_w,
               const float* __restrict__ r_erev, const float* __restrict__ gleak,
               const float* __restrict__ vleak, const float* __restrict__ cm,
               const float* __restrict__ W1, const float* __restrict__ b1,
               const float* __restrict__ W2, const float* __restrict__ b2,
               float* __restrict__ q_out, float* __restrict__ h_out) {
  // Packed transformed params: (k, c, w_signed, |w|). 64KB + 64KB = 128KB.
  __shared__ float4 sp[kD * kU];  // sensory, layout [d][i]
  __shared__ float4 rp[kU * kU];  // recurrent, layout [j][i]

  const int tid = threadIdx.x;
  for (int idx = tid; idx < kD * kU; idx += kBlock) {
    const float sg = s_sigma[idx];
    const float swa = softplus(s_w[idx]);
    sp[idx] = make_float4(-kLog2e * sg, kLog2e * sg * s_mu[idx],
                          swa * s_erev[idx], swa);
    const float rg = r_sigma[idx];
    const float rwa = softplus(r_w[idx]);
    rp[idx] = make_float4(-kLog2e * rg, kLog2e * rg * r_mu[idx],
                          rwa * r_erev[idx], rwa);
  }
  __syncthreads();

  const int lane = tid & 63;
  const int wid = tid >> 6;
  const int b0 = (blockIdx.x * kWaves + wid) * kEPW;  // this wave's 4 elements

  // Per-neuron (lane = i) scalars.
  const float gl   = softplus(gleak[lane]);
  const float glvl = gl * vleak[lane];
  const float cmt  = softplus(cm[lane]) * (float)kUnf;
  const float iw   = input_w[lane];
  const float ib   = input_b[lane];

  const float* ob[kEPW];
#pragma unroll
  for (int e = 0; e < kEPW; ++e) ob[e] = obs + (size_t)(b0 + e) * kT * kD;

  float v[kEPW], o[kEPW];
#pragma unroll
  for (int e = 0; e < kEPW; ++e) {
    v[e] = 0.0f;
    o[e] = ob[e][lane];  // prefetch t=0
  }

#pragma unroll 1
  for (int t = 0; t < kT; ++t) {
    // prefetch next timestep's obs; latency hides behind this iteration
    const int tn = (t + 1 < kT) ? (t + 1) : t;
    float nx[kEPW];
#pragma unroll
    for (int e = 0; e < kEPW; ++e) nx[e] = ob[e][tn * kD + lane];

    float xi[kEPW];
#pragma unroll
    for (int e = 0; e < kEPW; ++e) xi[e] = fmaf(o[e], iw, ib);

    // Sensory synapse sums (depend only on x; once per timestep).
    float ns[kEPW], ds[kEPW];
#pragma unroll
    for (int e = 0; e < kEPW; ++e) { ns[e] = 0.0f; ds[e] = 0.0f; }
#pragma unroll 16
    for (int d = 0; d < kD; ++d) {
      const float4 p = sp[d * kU + lane];
#pragma unroll
      for (int e = 0; e < kEPW; ++e) {
        const float xd = bcast(xi[e], d);
        const float ex = EXP2F(fmaf(p.x, xd, p.y));
        const float g = rcp_fast(1.0f + ex);
        ns[e] = fmaf(g, p.z, ns[e]);
        ds[e] = fmaf(g, p.w, ds[e]);
      }
    }

    // ODE unfolds.
#pragma unroll 1
    for (int u = 0; u < kUnf; ++u) {
      float num[kEPW], den[kEPW];
#pragma unroll
      for (int e = 0; e < kEPW; ++e) { num[e] = 0.0f; den[e] = 0.0f; }
#pragma unroll 16
      for (int j = 0; j < kU; ++j) {
        const float4 p = rp[j * kU + lane];
#pragma unroll
        for (int e = 0; e < kEPW; ++e) {
          const float vj = bcast(v[e], j);
          const float ex = EXP2F(fmaf(p.x, vj, p.y));
          const float g = rcp_fast(1.0f + ex);
          num[e] = fmaf(g, p.z, num[e]);
          den[e] = fmaf(g, p.w, den[e]);
        }
      }
#pragma unroll
      for (int e = 0; e < kEPW; ++e) {
        const float nt = fmaf(cmt, v[e], glvl) + num[e] + ns[e];
        const float dt = cmt + gl + den[e] + ds[e] + kEps;
        v[e] = nt * rcp_fast(dt);
      }
    }

#pragma unroll
    for (int e = 0; e < kEPW; ++e) o[e] = nx[e];
  }

  // hidden output
#pragma unroll
  for (int e = 0; e < kEPW; ++e) h_out[(size_t)(b0 + e) * kU + lane] = v[e];

  // Head: h1 = relu(v @ W1 + b1); q = h1 @ W2 + b2. Once per batch, cheap.
  float h1[kEPW];
#pragma unroll
  for (int e = 0; e < kEPW; ++e) h1[e] = b1[lane];
#pragma unroll 16
  for (int j = 0; j < kU; ++j) {
    const float w1 = W1[j * kQH + lane];
#pragma unroll
    for (int e = 0; e < kEPW; ++e) h1[e] = fmaf(bcast(v[e], j), w1, h1[e]);
  }
#pragma unroll
  for (int e = 0; e < kEPW; ++e) h1[e] = fmaxf(h1[e], 0.0f);

  float qa[kEPW][kA];
#pragma unroll
  for (int a = 0; a < kA; ++a) {
    const float w2 = W2[lane * kA + a];
#pragma unroll
    for (int e = 0; e < kEPW; ++e) qa[e][a] = h1[e] * w2;
  }
#pragma unroll
  for (int s = 32; s > 0; s >>= 1) {
#pragma unroll
    for (int a = 0; a < kA; ++a) {
#pragma unroll
      for (int e = 0; e < kEPW; ++e) qa[e][a] += __shfl_xor(qa[e][a], s, 64);
    }
  }
  if (lane == 0) {
#pragma unroll
    for (int a = 0; a < kA; ++a) {
#pragma unroll
      for (int e = 0; e < kEPW; ++e) {
        q_out[(size_t)(b0 + e) * kA + a] = qa[e][a] + b2[a];
      }
    }
  }
}

}  // namespace

extern "C" void kernel_launch(void* const* d_in, const int* in_sizes, int n_in,
                              void* d_out, int out_size, void* d_ws, size_t ws_size,
                              hipStream_t stream) {
  const float* obs     = (const float*)d_in[0];
  const float* input_w = (const float*)d_in[1];
  const float* input_b = (const float*)d_in[2];
  const float* s_mu    = (const float*)d_in[3];
  const float* s_sigma = (const float*)d_in[4];
  const float* s_w     = (const float*)d_in[5];
  const float* s_erev  = (const float*)d_in[6];
  const float* r_mu    = (const float*)d_in[7];
  const float* r_sigma = (const float*)d_in[8];
  const float* r_w     = (const float*)d_in[9];
  const float* r_erev  = (const float*)d_in[10];
  const float* gleak   = (const float*)d_in[11];
  const float* vleak   = (const float*)d_in[12];
  const float* cm      = (const float*)d_in[13];
  const float* W1      = (const float*)d_in[14];
  const float* b1      = (const float*)d_in[15];
  const float* W2      = (const float*)d_in[16];
  const float* b2      = (const float*)d_in[17];

  float* q_out = (float*)d_out;
  float* h_out = q_out + (size_t)kB * kA;

  hipLaunchKernelGGL(ltc_fused, dim3(kB / kBPB), dim3(kBlock), 0, stream,
                     obs, input_w, input_b, s_mu, s_sigma, s_w, s_erev,
                     r_mu, r_sigma, r_w, r_erev, gleak, vleak, cm,
                     W1, b1, W2, b2, q_out, h_out);
}